// Round 1
// baseline (536.272 us; speedup 1.0000x reference)
//
#include <hip/hip_runtime.h>

// out[b, m, p, q] = (1/SIDE^2) * sum_k vert[p,k] * hor[q,k]
//   m=0 (hf): K=64, x = {a0, b1-STRIP}, y = {b0, a1}
//     hor[q,k]  = relu(min(SIDE, (q+1)*SIDE - x_k, y_k - q*SIDE))
//     vert[p,k] = relu(min(SIDE, PY[p]+SIDE - y_k, x_k + STRIP - PY[p])), PY[p]=(511-p)*SIDE
//   m=1 (ri): K=32, x = a0, y = b0
//     hor[q,k]  = relu(min(SIDE, (q+1)*SIDE - x_k))
//     vert[p,k] = relu(min(SIDE, y_k - PY[p]))
// hor/vert normalized by 1/SIDE (absorbs /PIXEL_AREA, keeps values in [0,1] for bf16).
//
// Round-2 restructure: one block = one p-tile x ALL FOUR q-tiles.
//  - vert tile (v_s) + interval list staged ONCE per block (was 4x).
//  - hor tile (h_s) restaged per q-tile, but the inter-tile barriers are raw
//    s_barrier + lgkmcnt(0) ONLY (no vmcnt drain): the previous tile's 64 KiB
//    of stores stay in flight and drain underneath the staging VALU. The
//    compiler's __syncthreads() would emit s_waitcnt vmcnt(0) and convoy the
//    store pipe -- that drain was the theorized ~2x gap from the write floor.

#define P_DIM 512
#define TILE 128
#define NQT 4           // q-tiles per block
#define LDS_STRIDE 72   // 64 + 8 pad shorts; b128 frag reads land 2-way max on banks

constexpr float SIDEF     = (float)(1.5707963267948966 / 512.0);
constexpr float STRIPF    = (float)(1.5707963267948966);
constexpr float INV_SIDEF = (float)(512.0 / 1.5707963267948966);

typedef __attribute__((ext_vector_type(8))) short bf16x8;
typedef __attribute__((ext_vector_type(4))) float f32x4;

__device__ __forceinline__ unsigned short f2bf(float f) {
    unsigned int u = __float_as_uint(f);
    u += 0x7fffu + ((u >> 16) & 1u);   // round-to-nearest-even
    return (unsigned short)(u >> 16);
}

__global__ __launch_bounds__(256, 4)
void raster_kernel(const float* __restrict__ iv00, const float* __restrict__ iv01,
                   float* __restrict__ out)
{
    const int b  = blockIdx.z;
    const int m  = blockIdx.y;
    const int tp = blockIdx.x * TILE;   // p-tile origin (q-tiles looped inside)

    __shared__ unsigned short h_s[TILE * LDS_STRIDE];  // hor,  [q][k] bf16 normalized
    __shared__ unsigned short v_s[TILE * LDS_STRIDE];  // vert, [p][k]
    __shared__ float xk[64], yk[64];

    const int tid = threadIdx.x;

    // Load the batch's intervals and build the x/y endpoint lists (once per block).
    if (tid < 32) {
        float a0 = iv00[b * 64 + 2 * tid];
        float b0 = iv00[b * 64 + 2 * tid + 1];
        if (m == 0) {
            float a1 = iv01[b * 64 + 2 * tid];
            float b1 = iv01[b * 64 + 2 * tid + 1];
            xk[tid]      = a0;            yk[tid]      = b0;
            xk[tid + 32] = b1 - STRIPF;   yk[tid + 32] = a1;
        } else {
            xk[tid] = a0;  yk[tid] = b0;
        }
    }
    __syncthreads();   // vmcnt drain here is harmless: only the 64-float load is in flight

    // Per-thread fixed k (256 % K == 0); hoist k-dependent terms.
    const int kbits = (m == 0) ? 6 : 5;
    const int K     = 1 << kbits;
    const int k     = tid & (K - 1);
    const int r0    = tid >> kbits;
    const int rstep = 256 >> kbits;
    const float xv = xk[k], yv = yk[k];
    const float h_t1 = SIDEF - xv;            // h = min(SIDE, q0 + h_t1, yv - q0)
    const float v_t1 = SIDEF - yv;            // v = min(SIDE, py + v_t1, xv + STRIP - py)
    const float v_t2 = xv + STRIPF;

    // Stage vert tile ONCE (p rows fixed for the whole block).
    for (int r = r0; r < TILE; r += rstep) {
        float py = (float)(511 - (tp + r)) * SIDEF;  // PY[p]
        float v = (m == 0) ? fminf(SIDEF, fminf(py + v_t1, v_t2 - py))
                           : fminf(SIDEF, yv - py);
        v_s[r * LDS_STRIDE + k] = f2bf(fmaxf(v, 0.0f) * INV_SIDEF);
    }
    // Stage hor tile for q-tile 0.
    for (int r = r0; r < TILE; r += rstep) {
        float q0 = (float)r * SIDEF;                 // PX[q], tq = 0
        float h = (m == 0) ? fminf(SIDEF, fminf(q0 + h_t1, yv - q0))
                           : fminf(SIDEF, q0 + h_t1);
        h_s[r * LDS_STRIDE + k] = f2bf(fmaxf(h, 0.0f) * INV_SIDEF);
    }
    // Publish: LDS writes visible, but do NOT drain vmcnt.
    asm volatile("s_waitcnt lgkmcnt(0)\n\ts_barrier" ::: "memory");

    const int lane = tid & 63;
    const int wave = tid >> 6;     // wave owns q-rows [wave*32, wave*32+32)
    const int col  = lane & 15;    // A row (q) / B row (p) / D col (p)
    const int quad = lane >> 4;    // k-block select; D row group (q)
    const int nks  = (m == 0) ? 2 : 1;

    float* obase = out + (size_t)(b * 2 + m) * P_DIM * P_DIM;

    for (int t = 0; t < NQT; ++t) {
        f32x4 acc[2][8];           // [q-subtile][p-subtile]
        #pragma unroll
        for (int qs = 0; qs < 2; ++qs)
            #pragma unroll
            for (int ps = 0; ps < 8; ++ps)
                acc[qs][ps] = (f32x4){0.f, 0.f, 0.f, 0.f};

        #pragma unroll
        for (int ks = 0; ks < 2; ++ks) {
            if (ks >= nks) break;
            const int k0 = ks * 32 + quad * 8;
            bf16x8 a0 = *(const bf16x8*)&h_s[(wave * 32 +      col) * LDS_STRIDE + k0];
            bf16x8 a1 = *(const bf16x8*)&h_s[(wave * 32 + 16 + col) * LDS_STRIDE + k0];
            #pragma unroll
            for (int ps = 0; ps < 8; ++ps) {
                bf16x8 bf = *(const bf16x8*)&v_s[(ps * 16 + col) * LDS_STRIDE + k0];
                acc[0][ps] = __builtin_amdgcn_mfma_f32_16x16x32_bf16(a0, bf, acc[0][ps], 0, 0, 0);
                acc[1][ps] = __builtin_amdgcn_mfma_f32_16x16x32_bf16(a1, bf, acc[1][ps], 0, 0, 0);
            }
        }

        // Stores: D row (= quad*4+reg) walks q; float4 stores, 16 B/lane.
        // Per instr: 16 rows x 64 B contiguous; qs pair completes 128 B/row.
        const int qbase = t * TILE + wave * 32 + quad * 4;
        #pragma unroll
        for (int ps = 0; ps < 8; ++ps) {
            int p = tp + ps * 16 + col;
            float* rowp = obase + (size_t)p * P_DIM;
            #pragma unroll
            for (int qs = 0; qs < 2; ++qs) {
                *(f32x4*)&rowp[qbase + qs * 16] = acc[qs][ps];
            }
        }

        if (t < NQT - 1) {
            // All waves' frag reads of h_s completed before their MFMAs issued;
            // raw barrier (NO waitcnt) lets this tile's stores keep draining.
            asm volatile("s_barrier" ::: "memory");
            const int tq = (t + 1) * TILE;
            for (int r = r0; r < TILE; r += rstep) {
                float q0 = (float)(tq + r) * SIDEF;
                float h = (m == 0) ? fminf(SIDEF, fminf(q0 + h_t1, yv - q0))
                                   : fminf(SIDEF, q0 + h_t1);
                h_s[r * LDS_STRIDE + k] = f2bf(fmaxf(h, 0.0f) * INV_SIDEF);
            }
            // Publish next h tile; again LDS-only wait, stores stay in flight.
            asm volatile("s_waitcnt lgkmcnt(0)\n\ts_barrier" ::: "memory");
        }
    }
}

extern "C" void kernel_launch(void* const* d_in, const int* in_sizes, int n_in,
                              void* d_out, int out_size, void* d_ws, size_t ws_size,
                              hipStream_t stream) {
    const float* iv00 = (const float*)d_in[0];
    const float* iv01 = (const float*)d_in[1];
    float* out = (float*)d_out;
    dim3 grid(P_DIM / TILE, 2, 256);   // 4 p-tiles x 2 matrices x 256 batches
    raster_kernel<<<grid, dim3(256), 0, stream>>>(iv00, iv01, out);
}